// Round 10
// baseline (169.263 us; speedup 1.0000x reference)
//
#include <hip/hip_runtime.h>

typedef _Float16 half8 __attribute__((ext_vector_type(8)));
typedef float floatx4 __attribute__((ext_vector_type(4)));

__device__ __forceinline__ void gld_lds16(const void* g, void* l) {
  __builtin_amdgcn_global_load_lds(
      (const __attribute__((address_space(1))) void*)g,
      (__attribute__((address_space(3))) void*)l, 16, 0, 0);
}

#define SB() __builtin_amdgcn_sched_barrier(0)
#define LGKM(n) asm volatile("s_waitcnt lgkmcnt(" #n ")" ::: "memory")
#define VMC(n) asm volatile("s_waitcnt vmcnt(" #n ")" ::: "memory")
#define BAR() __builtin_amdgcn_s_barrier()
#define PRIO1() __builtin_amdgcn_s_setprio(1)
#define PRIO0() __builtin_amdgcn_s_setprio(0)

// ======= QKV with fused x f32->f16: A reg-staged, B gld_lds ==================
// 128x128 tile, BK=64, 4 waves, 64KB LDS, 2 wg/CU, 1536 wgs.
// Per tile t: top: issue A(t+1) f32 loads -> regs + B(t+1) gld_lds (p^1).
// End: VMC(0) (issued ~2000cyc ago) -> cvt+ds_write A(t+1) -> LGKM(0) -> BAR.
__global__ __launch_bounds__(256, 2) void gemmq(
    const float* __restrict__ Xf, const _Float16* __restrict__ Wg,
    _Float16* __restrict__ Cg, const float* __restrict__ bcat) {
  constexpr int NK = 16, NWG = 1536;
  int g = (int)blockIdx.x;
  g = (g & 7) * (NWG / 8) + (g >> 3);
  const int tm = g / 24, tn = g % 24;
  const int row0 = tm * 128, col0 = tn * 128;
  const float* Ap = Xf + (size_t)row0 * 1024;
  const _Float16* Bp = Wg + (size_t)col0 * 1024;

  __shared__ _Float16 lds[32768];  // A[2][8192] @0, B[2][8192] @16384
  const int tid = threadIdx.x, lane = tid & 63, wid = tid >> 6;
  const int wm = wid >> 1, wn = wid & 1;
  const int wrow = wm * 64, wcol = wn * 64;
  const int fr = lane & 15, u = lane >> 4, w7 = lane & 7;
  const int k0e = ((u ^ w7) << 3), k1e = (((4 + u) ^ w7) << 3);
  const int srow = tid >> 3;
  const int sgl = (((tid & 7) ^ (srow & 7)) << 3);

  floatx4 acc[4][4] = {};
  half8 aF[8], bF[8];
  float4 rA[8];

  auto loadA = [&](int kt) {  // 8 x global_load_dwordx4 (f32 x)
#pragma unroll
    for (int c = 0; c < 4; ++c) {
      const float* s = Ap + (size_t)(c * 32 + srow) * 1024 + kt + sgl;
      rA[c * 2 + 0] = ((const float4*)s)[0];
      rA[c * 2 + 1] = ((const float4*)s)[1];
    }
  };
  auto writeA = [&](int p) {  // cvt + 4 x ds_write_b128
#pragma unroll
    for (int c = 0; c < 4; ++c) {
      half8 h;
      h[0] = (_Float16)rA[c * 2].x;     h[1] = (_Float16)rA[c * 2].y;
      h[2] = (_Float16)rA[c * 2].z;     h[3] = (_Float16)rA[c * 2].w;
      h[4] = (_Float16)rA[c * 2 + 1].x; h[5] = (_Float16)rA[c * 2 + 1].y;
      h[6] = (_Float16)rA[c * 2 + 1].z; h[7] = (_Float16)rA[c * 2 + 1].w;
      *(half8*)&lds[p * 8192 + c * 2048 + tid * 8] = h;
    }
  };
  auto stageB = [&](int kt, int p) {  // 4 x gld_lds16
#pragma unroll
    for (int c = 0; c < 4; ++c)
      gld_lds16(Bp + (size_t)(c * 32 + srow) * 1024 + kt + sgl,
                &lds[16384 + p * 8192 + c * 2048 + tid * 8]);
  };
  auto ldA4 = [&](int p) {
#pragma unroll
    for (int mf = 0; mf < 4; ++mf) {
      const int ro = p * 8192 + (wrow + mf * 16 + fr) * 64;
      aF[mf * 2 + 0] = *(const half8*)&lds[ro + k0e];
      aF[mf * 2 + 1] = *(const half8*)&lds[ro + k1e];
    }
  };
  auto ldB2 = [&](int p, int nf0) {
#pragma unroll
    for (int nf = 0; nf < 2; ++nf) {
      const int ro = 16384 + p * 8192 + (wcol + (nf0 + nf) * 16 + fr) * 64;
      bF[(nf0 + nf) * 2 + 0] = *(const half8*)&lds[ro + k0e];
      bF[(nf0 + nf) * 2 + 1] = *(const half8*)&lds[ro + k1e];
    }
  };
  auto burst = [&](int nf0) {
#pragma unroll
    for (int mf = 0; mf < 4; ++mf)
#pragma unroll
      for (int nf = 0; nf < 2; ++nf)
#pragma unroll
        for (int kk = 0; kk < 2; ++kk)
          acc[mf][nf0 + nf] = __builtin_amdgcn_mfma_f32_16x16x32_f16(
              aF[mf * 2 + kk], bF[(nf0 + nf) * 2 + kk], acc[mf][nf0 + nf], 0, 0, 0);
  };

  // prologue: tile 0
  loadA(0);
  stageB(0, 0);
  VMC(0);
  writeA(0);
  LGKM(0);
  BAR();

#pragma unroll 1
  for (int t = 0; t < NK; ++t) {
    const int p = t & 1;
    if (t + 1 < NK) { loadA(t * 64 + 64); stageB(t * 64 + 64, p ^ 1); }
    SB();
    ldA4(p); SB(); ldB2(p, 0); SB(); ldB2(p, 2); SB();
    LGKM(4); SB(); PRIO1(); burst(0); PRIO0(); SB();
    LGKM(0); SB(); PRIO1(); burst(2); PRIO0(); SB();
    if (t + 1 < NK) {
      VMC(0);        // A-reg loads + B gld_lds for t+1, issued a tile ago
      writeA(p ^ 1); // cvt + ds_write into freed A slot
      LGKM(0);       // drain own ds_writes before publish
    }
    BAR();
  }

  const int r0 = row0 + wrow + u * 4;
  const int c0 = col0 + wcol + fr;
#pragma unroll
  for (int mf = 0; mf < 4; ++mf)
#pragma unroll
    for (int nf = 0; nf < 4; ++nf) {
      const int col = c0 + nf * 16;
      const float badd = bcat[col];
#pragma unroll
      for (int j = 0; j < 4; ++j)
        Cg[(size_t)(r0 + mf * 16 + j) * 3072 + col] = (_Float16)(acc[mf][nf][j] + badd);
    }
}

// ======== scores: 256x256 8-phase (R9), A=Q B=K (stride 3072) ===============
__global__ __launch_bounds__(512, 2) void gemm8x(const _Float16* __restrict__ QKV,
                                                 _Float16* __restrict__ Sc) {
  int g = (int)blockIdx.x;
  g = (g & 7) * 32 + (g >> 3);
  const int z = g >> 6, r = g & 63, tm = r >> 3, tn = r & 7;
  const int row0 = tm * 256, col0 = tn * 256;
  const _Float16* Ap = QKV + ((size_t)z * 2048 + row0) * 3072;
  const _Float16* Bp = QKV + ((size_t)z * 2048 + col0) * 3072 + 1024;
  _Float16* C16 = Sc + (size_t)z * 4194304;

  __shared__ _Float16 lds[65536];
  const int tid = threadIdx.x, lane = tid & 63, wid = tid >> 6;
  const int wm = wid >> 2, wn = wid & 3;
  const int fr = lane & 15, u = lane >> 4, w7 = lane & 7;
  const int k0e = ((u ^ w7) << 3), k1e = (((4 + u) ^ w7) << 3);
  const int srow = tid >> 3;
  const int sgl = (((tid & 7) ^ (srow & 7)) << 3);

  floatx4 acc[8][4] = {};
  half8 aF[8], bF0[4], bF1[4];

  auto stg = [&](const _Float16* Gp, int rowoff, int kt, int dst) {
    gld_lds16(Gp + (size_t)(rowoff + srow) * 3072 + kt + sgl, &lds[dst + tid * 8]);
  };
  auto stA = [&](int kt, int p, int h) {
    stg(Ap, h * 128, kt, p * 16384 + h * 8192);
    stg(Ap, h * 128 + 64, kt, p * 16384 + h * 8192 + 4096);
  };
  auto stB = [&](int kt, int p, int h) {
    stg(Bp, h * 128, kt, 32768 + p * 16384 + h * 8192);
    stg(Bp, h * 128 + 64, kt, 32768 + p * 16384 + h * 8192 + 4096);
  };
  auto ldA = [&](int p, int mh) {
#pragma unroll
    for (int mf = 0; mf < 4; ++mf) {
      const int ro = p * 16384 + (wm * 128 + mh * 64 + mf * 16 + fr) * 64;
      aF[mf * 2 + 0] = *(const half8*)&lds[ro + k0e];
      aF[mf * 2 + 1] = *(const half8*)&lds[ro + k1e];
    }
  };
  auto ldB = [&](int p, int nh, half8* bF) {
#pragma unroll
    for (int nf = 0; nf < 2; ++nf) {
      const int ro = 32768 + p * 16384 + (wn * 64 + nh * 32 + nf * 16 + fr) * 64;
      bF[nf * 2 + 0] = *(const half8*)&lds[ro + k0e];
      bF[nf * 2 + 1] = *(const half8*)&lds[ro + k1e];
    }
  };
  auto Q = [&](int mh, int nh, half8* bF) {
#pragma unroll
    for (int mf = 0; mf < 4; ++mf)
#pragma unroll
      for (int nf = 0; nf < 2; ++nf)
#pragma unroll
        for (int kk = 0; kk < 2; ++kk)
          acc[mh * 4 + mf][nh * 2 + nf] = __builtin_amdgcn_mfma_f32_16x16x32_f16(
              aF[mf * 2 + kk], bF[nf * 2 + kk], acc[mh * 4 + mf][nh * 2 + nf], 0, 0, 0);
  };

  stA(0, 0, 0); stA(0, 0, 1); stB(0, 0, 0); stB(0, 0, 1);
  stB(64, 1, 0); stB(64, 1, 1);
  VMC(4); BAR();

  constexpr int NK = 16;
#pragma unroll 1
  for (int t = 0; t < NK; ++t) {
    const int p = t & 1, kt = t * 64;
    ldA(p, 0); SB(); ldB(p, 0, bF0); SB();
    if (t + 1 < NK) stA(kt + 64, p ^ 1, 0);
    SB(); LGKM(8); SB();
    BAR(); LGKM(0); SB(); PRIO1(); Q(0, 0, bF0); PRIO0(); SB(); BAR();
    ldB(p, 1, bF1); SB();
    if (t + 1 < NK) stA(kt + 64, p ^ 1, 1);
    SB();
    BAR(); LGKM(0); SB(); PRIO1(); Q(0, 1, bF1); PRIO0(); SB(); VMC(8); BAR();
    ldA(p, 1); SB();
    if (t + 2 < NK) stB(kt + 128, p, 0);
    SB();
    BAR(); LGKM(0); SB(); PRIO1(); Q(1, 0, bF0); PRIO0(); SB(); BAR();
    if (t + 2 < NK) stB(kt + 128, p, 1);
    SB();
    BAR(); PRIO1(); Q(1, 1, bF1); PRIO0(); SB();
    if (t + 2 < NK) { VMC(6); } else if (t + 1 < NK) { VMC(0); }
    BAR();
  }

  const int r0 = row0 + wm * 128 + u * 4;
  const int c0 = col0 + wn * 64 + fr;
#pragma unroll
  for (int mf = 0; mf < 8; ++mf)
#pragma unroll
    for (int nf = 0; nf < 4; ++nf)
#pragma unroll
      for (int j = 0; j < 4; ++j)
        C16[(size_t)(r0 + mf * 16 + j) * 2048 + c0 + nf * 16] = (_Float16)acc[mf][nf][j];
}

// ===== PV: desync ring GEMM (R8): 128x128, BK=64, 4 waves, 2 wg/CU, 512 wg ==
__global__ __launch_bounds__(256, 2) void gemmp(
    const _Float16* __restrict__ Scp, const _Float16* __restrict__ Vt,
    float* __restrict__ Out) {
  constexpr int NK = 32, NWG = 512;
  int g = (int)blockIdx.x;
  g = (g & 7) * (NWG / 8) + (g >> 3);
  const int z = g >> 7, r = g & 127, tm = r >> 3, tn = r & 7;
  const int row0 = tm * 128, col0 = tn * 128;
  const _Float16* Ap = Scp + (size_t)z * 4194304 + (size_t)row0 * 2048;
  const _Float16* Bp = Vt + (size_t)z * 2097152 + (size_t)col0 * 2048;
  float* C32 = Out + (size_t)z * 2097152;

  __shared__ _Float16 lds[32768];
  const int tid = threadIdx.x, lane = tid & 63, wid = tid >> 6;
  const int wm = wid >> 1, wn = wid & 1;
  const int wrow = wm * 64, wcol = wn * 64;
  const int fr = lane & 15, u = lane >> 4, w7 = lane & 7;
  const int k0e = ((u ^ w7) << 3), k1e = (((4 + u) ^ w7) << 3);
  const int srow = tid >> 3;
  const int sgl = (((tid & 7) ^ (srow & 7)) << 3);

  floatx4 acc[4][4] = {};
  half8 aF[8], bF[8];

  auto stage1 = [&](const _Float16* Gp, int rowoff, int kt, int dst) {
    gld_lds16(Gp + (size_t)(rowoff + srow) * 2048 + kt + sgl, &lds[dst + tid * 8]);
  };
  auto stageT = [&](int kt, int p) {
#pragma unroll
    for (int c = 0; c < 4; ++c) stage1(Ap, c * 32, kt, p * 8192 + c * 2048);
#pragma unroll
    for (int c = 0; c < 4; ++c) stage1(Bp, c * 32, kt, 16384 + p * 8192 + c * 2048);
  };
  auto ldA4 = [&](int p) {
#pragma unroll
    for (int mf = 0; mf < 4; ++mf) {
      const int ro = p * 8192 + (wrow + mf * 16 + fr) * 64;
      aF[mf * 2 + 0] = *(const half8*)&lds[ro + k0e];
      aF[mf * 2 + 1] = *(const half8*)&lds[ro + k1e];
    }
  };
  auto ldB2 = [&](int p, int nf0) {
#pragma unroll
    for (int nf = 0; nf < 2; ++nf) {
      const int ro = 16384 + p * 8192 + (wcol + (nf0 + nf) * 16 + fr) * 64;
      bF[(nf0 + nf) * 2 + 0] = *(const half8*)&lds[ro + k0e];
      bF[(nf0 + nf) * 2 + 1] = *(const half8*)&lds[ro + k1e];
    }
  };
  auto burst = [&](int nf0) {
#pragma unroll
    for (int mf = 0; mf < 4; ++mf)
#pragma unroll
      for (int nf = 0; nf < 2; ++nf)
#pragma unroll
        for (int kk = 0; kk < 2; ++kk)
          acc[mf][nf0 + nf] = __builtin_amdgcn_mfma_f32_16x16x32_f16(
              aF[mf * 2 + kk], bF[(nf0 + nf) * 2 + kk], acc[mf][nf0 + nf], 0, 0, 0);
  };

  stageT(0, 0);
  VMC(0);
  BAR();

#pragma unroll 1
  for (int t = 0; t < NK; ++t) {
    const int p = t & 1;
    if (t + 1 < NK) stageT(t * 64 + 64, p ^ 1);
    SB();
    ldA4(p); SB(); ldB2(p, 0); SB(); ldB2(p, 2); SB();
    LGKM(4); SB(); PRIO1(); burst(0); PRIO0(); SB();
    LGKM(0); SB(); PRIO1(); burst(2); PRIO0(); SB();
    if (t + 1 < NK) VMC(0);
    BAR();
  }

  const int r0 = row0 + wrow + u * 4;
  const int c0 = col0 + wcol + fr;
#pragma unroll
  for (int mf = 0; mf < 4; ++mf)
#pragma unroll
    for (int nf = 0; nf < 4; ++nf)
#pragma unroll
      for (int j = 0; j < 4; ++j)
        C32[(size_t)(r0 + mf * 16 + j) * 1024 + c0 + nf * 16] = acc[mf][nf][j];
}

// --------- prep2: W cvt (blocks 0..1535) + bias concat (1536..1547) ----------
__global__ __launch_bounds__(256) void prep2(
    const float* __restrict__ wq, const float* __restrict__ wk,
    const float* __restrict__ wv, const float* __restrict__ bq,
    const float* __restrict__ bk, const float* __restrict__ bv,
    _Float16* __restrict__ W16, float* __restrict__ bcat) {
  const int b = blockIdx.x, t = threadIdx.x;
  if (b < 1536) {
    const int idx = b * 256 + t;  // [0, 393216)
    const int m = idx >> 17, j = idx & 131071;
    const float* src = (m == 0 ? wq : (m == 1 ? wk : wv)) + (size_t)j * 8;
    const float4* p = (const float4*)src;
    float4 a = p[0], bb = p[1];
    half8 h;
    h[0] = (_Float16)a.x; h[1] = (_Float16)a.y; h[2] = (_Float16)a.z; h[3] = (_Float16)a.w;
    h[4] = (_Float16)bb.x; h[5] = (_Float16)bb.y; h[6] = (_Float16)bb.z; h[7] = (_Float16)bb.w;
    *(half8*)(W16 + (size_t)m * 1048576 + (size_t)j * 8) = h;
  } else {
    const int i = (b - 1536) * 256 + t;  // [0, 3072)
    const float* s = i < 1024 ? bq : (i < 2048 ? bk : bv);
    bcat[i] = s[i & 1023];
  }
}

// V = QKV cols 2048.. (stride 3072) -> Vt[4][1024][2048]
__global__ __launch_bounds__(256) void transpose_v(const _Float16* __restrict__ QKV,
                                                   _Float16* __restrict__ Vt) {
  __shared__ _Float16 t[32][36];
  const int b = blockIdx.z;
  const int e0 = blockIdx.x * 32;
  const int s0 = blockIdx.y * 32;
  const int tid = threadIdx.x;
  const int r = tid >> 3;
  const int c4 = (tid & 7) * 4;
  const _Float16* src = QKV + (size_t)(b * 2048 + s0 + r) * 3072 + 2048 + e0 + c4;
#pragma unroll
  for (int j = 0; j < 4; ++j) t[r][c4 + j] = src[j];
  __syncthreads();
  _Float16* dst = Vt + ((size_t)b * 1024 + e0 + r) * 2048 + s0 + c4;
#pragma unroll
  for (int j = 0; j < 4; ++j) dst[j] = t[c4 + j][r];
}

__global__ __launch_bounds__(256) void softmax_rows_f16(_Float16* __restrict__ S) {
  __shared__ float red[4];
  _Float16* s = S + (size_t)blockIdx.x * 2048;
  const int tid = threadIdx.x;
  float v[8];
  {
    half8 h = *(const half8*)(s + tid * 8);
#pragma unroll
    for (int j = 0; j < 8; ++j) v[j] = (float)h[j];
  }
  float m = v[0];
#pragma unroll
  for (int j = 1; j < 8; ++j) m = fmaxf(m, v[j]);
#pragma unroll
  for (int off = 32; off > 0; off >>= 1) m = fmaxf(m, __shfl_xor(m, off));
  if ((tid & 63) == 0) red[tid >> 6] = m;
  __syncthreads();
  m = fmaxf(fmaxf(red[0], red[1]), fmaxf(red[2], red[3]));
  float sum = 0.f;
#pragma unroll
  for (int j = 0; j < 8; ++j) { v[j] = __expf(v[j] - m); sum += v[j]; }
#pragma unroll
  for (int off = 32; off > 0; off >>= 1) sum += __shfl_xor(sum, off);
  __syncthreads();
  if ((tid & 63) == 0) red[tid >> 6] = sum;
  __syncthreads();
  sum = red[0] + red[1] + red[2] + red[3];
  const float inv = 1.0f / sum;
  half8 h;
#pragma unroll
  for (int j = 0; j < 8; ++j) h[j] = (_Float16)(v[j] * inv);
  *(half8*)(s + tid * 8) = h;
}

extern "C" void kernel_launch(void* const* d_in, const int* in_sizes, int n_in,
                              void* d_out, int out_size, void* d_ws, size_t ws_size,
                              hipStream_t stream) {
  (void)in_sizes; (void)n_in; (void)out_size;
  const float* x  = (const float*)d_in[0];
  const float* Wq = (const float*)d_in[1];
  const float* bq = (const float*)d_in[2];
  const float* Wk = (const float*)d_in[3];
  const float* bk = (const float*)d_in[4];
  const float* Wv = (const float*)d_in[5];
  const float* bv = (const float*)d_in[6];
  float* out = (float*)d_out;

  char* ws = (char*)d_ws;
  size_t off = 0;
  auto alloc = [&](size_t bytes) {
    char* p = ws + off;
    off += (bytes + 255) & ~255ull;
    return p;
  };
  _Float16* W16  = (_Float16*)alloc(3072ull * 1024 * 2);
  _Float16* QKV  = (_Float16*)alloc(8192ull * 3072 * 2);
  _Float16* Vt   = (_Float16*)alloc(4096ull * 1024 * 4);
  _Float16* Sc   = (_Float16*)alloc(4ull * 2048 * 2048 * 2);
  float*    bcat = (float*)alloc(3072 * 4);
  if (off > ws_size) return;

  prep2<<<1548, 256, 0, stream>>>(Wq, Wk, Wv, bq, bk, bv, W16, bcat);

  gemmq<<<1536, 256, 0, stream>>>(x, W16, QKV, bcat);
  transpose_v<<<dim3(32, 64, 4), 256, 0, stream>>>(QKV, Vt);

  gemm8x<<<256, 512, 0, stream>>>(QKV, Sc);
  softmax_rows_f16<<<8192, 256, 0, stream>>>(Sc);
  gemmp<<<512, 256, 0, stream>>>(Sc, Vt, out);
}

// Round 11
// 158.820 us; speedup vs baseline: 1.0658x; 1.0658x over previous
//
#include <hip/hip_runtime.h>

typedef _Float16 half8 __attribute__((ext_vector_type(8)));
typedef float floatx4 __attribute__((ext_vector_type(4)));

__device__ __forceinline__ void gld_lds16(const void* g, void* l) {
  __builtin_amdgcn_global_load_lds(
      (const __attribute__((address_space(1))) void*)g,
      (__attribute__((address_space(3))) void*)l, 16, 0, 0);
}

#define SB() __builtin_amdgcn_sched_barrier(0)
#define LGKM(n) asm volatile("s_waitcnt lgkmcnt(" #n ")" ::: "memory")
#define VMC(n) asm volatile("s_waitcnt vmcnt(" #n ")" ::: "memory")
#define BAR() __builtin_amdgcn_s_barrier()
#define PRIO1() __builtin_amdgcn_s_setprio(1)
#define PRIO0() __builtin_amdgcn_s_setprio(0)

// ======== scores: m201-style 256x256 8-phase, A=Q B=K (stride 3072) =========
__global__ __launch_bounds__(512, 2) void gemm8x(const _Float16* __restrict__ QKV,
                                                 _Float16* __restrict__ Sc) {
  int g = (int)blockIdx.x;
  g = (g & 7) * 32 + (g >> 3);  // XCD swizzle, 256 % 8 == 0
  const int z = g >> 6, r = g & 63, tm = r >> 3, tn = r & 7;
  const int row0 = tm * 256, col0 = tn * 256;
  const _Float16* Ap = QKV + ((size_t)z * 2048 + row0) * 3072;
  const _Float16* Bp = QKV + ((size_t)z * 2048 + col0) * 3072 + 1024;
  _Float16* C16 = Sc + (size_t)z * 4194304;

  __shared__ _Float16 lds[65536];  // A[2][16384] @0, B[2][16384] @32768
  const int tid = threadIdx.x, lane = tid & 63, wid = tid >> 6;
  const int wm = wid >> 2, wn = wid & 3;
  const int fr = lane & 15, u = lane >> 4, w7 = lane & 7;
  const int k0e = ((u ^ w7) << 3), k1e = (((4 + u) ^ w7) << 3);
  const int srow = tid >> 3;
  const int sgl = (((tid & 7) ^ (srow & 7)) << 3);

  floatx4 acc[8][4] = {};
  half8 aF[8], bF0[4], bF1[4];

  auto stg = [&](const _Float16* Gp, int rowoff, int kt, int dst) {
    gld_lds16(Gp + (size_t)(rowoff + srow) * 3072 + kt + sgl, &lds[dst + tid * 8]);
  };
  auto stA = [&](int kt, int p, int h) {
    stg(Ap, h * 128, kt, p * 16384 + h * 8192);
    stg(Ap, h * 128 + 64, kt, p * 16384 + h * 8192 + 4096);
  };
  auto stB = [&](int kt, int p, int h) {
    stg(Bp, h * 128, kt, 32768 + p * 16384 + h * 8192);
    stg(Bp, h * 128 + 64, kt, 32768 + p * 16384 + h * 8192 + 4096);
  };
  auto ldA = [&](int p, int mh) {
#pragma unroll
    for (int mf = 0; mf < 4; ++mf) {
      const int ro = p * 16384 + (wm * 128 + mh * 64 + mf * 16 + fr) * 64;
      aF[mf * 2 + 0] = *(const half8*)&lds[ro + k0e];
      aF[mf * 2 + 1] = *(const half8*)&lds[ro + k1e];
    }
  };
  auto ldB = [&](int p, int nh, half8* bF) {
#pragma unroll
    for (int nf = 0; nf < 2; ++nf) {
      const int ro = 32768 + p * 16384 + (wn * 64 + nh * 32 + nf * 16 + fr) * 64;
      bF[nf * 2 + 0] = *(const half8*)&lds[ro + k0e];
      bF[nf * 2 + 1] = *(const half8*)&lds[ro + k1e];
    }
  };
  auto Q = [&](int mh, int nh, half8* bF) {
#pragma unroll
    for (int mf = 0; mf < 4; ++mf)
#pragma unroll
      for (int nf = 0; nf < 2; ++nf)
#pragma unroll
        for (int kk = 0; kk < 2; ++kk)
          acc[mh * 4 + mf][nh * 2 + nf] = __builtin_amdgcn_mfma_f32_16x16x32_f16(
              aF[mf * 2 + kk], bF[nf * 2 + kk], acc[mh * 4 + mf][nh * 2 + nf], 0, 0, 0);
  };

  stA(0, 0, 0); stA(0, 0, 1); stB(0, 0, 0); stB(0, 0, 1);
  stB(64, 1, 0); stB(64, 1, 1);
  VMC(4); BAR();

  constexpr int NK = 16;
#pragma unroll 1
  for (int t = 0; t < NK; ++t) {
    const int p = t & 1, kt = t * 64;
    ldA(p, 0); SB(); ldB(p, 0, bF0); SB();
    if (t + 1 < NK) stA(kt + 64, p ^ 1, 0);
    SB(); LGKM(8); SB();
    BAR(); LGKM(0); SB(); PRIO1(); Q(0, 0, bF0); PRIO0(); SB(); BAR();
    ldB(p, 1, bF1); SB();
    if (t + 1 < NK) stA(kt + 64, p ^ 1, 1);
    SB();
    BAR(); LGKM(0); SB(); PRIO1(); Q(0, 1, bF1); PRIO0(); SB(); VMC(8); BAR();
    ldA(p, 1); SB();
    if (t + 2 < NK) stB(kt + 128, p, 0);
    SB();
    BAR(); LGKM(0); SB(); PRIO1(); Q(1, 0, bF0); PRIO0(); SB(); BAR();
    if (t + 2 < NK) stB(kt + 128, p, 1);
    SB();
    BAR(); PRIO1(); Q(1, 1, bF1); PRIO0(); SB();
    if (t + 2 < NK) { VMC(6); } else if (t + 1 < NK) { VMC(0); }
    BAR();
  }

  const int r0 = row0 + wm * 128 + u * 4;
  const int c0 = col0 + wn * 64 + fr;
#pragma unroll
  for (int mf = 0; mf < 8; ++mf)
#pragma unroll
    for (int nf = 0; nf < 4; ++nf)
#pragma unroll
      for (int j = 0; j < 4; ++j)
        C16[(size_t)(r0 + mf * 16 + j) * 2048 + c0 + nf * 16] = (_Float16)acc[mf][nf][j];
}

// ===== desync ring GEMM: 128x128 tile, BK=64, 4 waves, 2 wg/CU ==============
// MODE 0: QKV  A=x16[8192,1024] B=Wcat[3072,1024] -> f16[8192,3072]+bias, 1536 wg
// MODE 2: PV   A=Sc[z][2048,2048] B=Vt[z][1024,2048] -> f32 out, 512 wg
template <int MODE>
__global__ __launch_bounds__(256, 2) void gemmd(
    const _Float16* __restrict__ Ag, const _Float16* __restrict__ Bg,
    void* __restrict__ Cg, const float* __restrict__ bcat) {
  constexpr int KS   = MODE == 0 ? 1024 : 2048;
  constexpr int NK   = MODE == 2 ? 32 : 16;
  constexpr int NWG  = MODE == 0 ? 1536 : 512;
  constexpr int CSTR = MODE == 0 ? 3072 : 1024;

  int g = (int)blockIdx.x;
  g = (g & 7) * (NWG / 8) + (g >> 3);

  int row0, col0;
  const _Float16 *Ap, *Bp;
  _Float16* C16 = nullptr;
  float* C32 = nullptr;
  if constexpr (MODE == 0) {
    const int tm = g / 24, tn = g % 24;
    row0 = tm * 128; col0 = tn * 128;
    Ap = Ag + (size_t)row0 * 1024;
    Bp = Bg + (size_t)col0 * 1024;
    C16 = (_Float16*)Cg;
  } else {
    const int z = g >> 7, r = g & 127, tm = r >> 3, tn = r & 7;
    row0 = tm * 128; col0 = tn * 128;
    Ap = Ag + (size_t)z * 4194304 + (size_t)row0 * 2048;
    Bp = Bg + (size_t)z * 2097152 + (size_t)col0 * 2048;
    C32 = (float*)Cg + (size_t)z * 2097152;
  }

  __shared__ _Float16 lds[32768];
  const int tid = threadIdx.x, lane = tid & 63, wid = tid >> 6;
  const int wm = wid >> 1, wn = wid & 1;
  const int wrow = wm * 64, wcol = wn * 64;
  const int fr = lane & 15, u = lane >> 4, w7 = lane & 7;
  const int k0e = ((u ^ w7) << 3), k1e = (((4 + u) ^ w7) << 3);
  const int srow = tid >> 3;
  const int sgl = (((tid & 7) ^ (srow & 7)) << 3);

  floatx4 acc[4][4] = {};
  half8 aF[8], bF[8];

  auto stage1 = [&](const _Float16* Gp, int rowoff, int kt, int dst) {
    gld_lds16(Gp + (size_t)(rowoff + srow) * KS + kt + sgl, &lds[dst + tid * 8]);
  };
  auto stageT = [&](int kt, int p) {
#pragma unroll
    for (int c = 0; c < 4; ++c) stage1(Ap, c * 32, kt, p * 8192 + c * 2048);
#pragma unroll
    for (int c = 0; c < 4; ++c) stage1(Bp, c * 32, kt, 16384 + p * 8192 + c * 2048);
  };
  auto ldA4 = [&](int p) {
#pragma unroll
    for (int mf = 0; mf < 4; ++mf) {
      const int ro = p * 8192 + (wrow + mf * 16 + fr) * 64;
      aF[mf * 2 + 0] = *(const half8*)&lds[ro + k0e];
      aF[mf * 2 + 1] = *(const half8*)&lds[ro + k1e];
    }
  };
  auto ldB2 = [&](int p, int nf0) {
#pragma unroll
    for (int nf = 0; nf < 2; ++nf) {
      const int ro = 16384 + p * 8192 + (wcol + (nf0 + nf) * 16 + fr) * 64;
      bF[(nf0 + nf) * 2 + 0] = *(const half8*)&lds[ro + k0e];
      bF[(nf0 + nf) * 2 + 1] = *(const half8*)&lds[ro + k1e];
    }
  };
  auto burst = [&](int nf0) {
#pragma unroll
    for (int mf = 0; mf < 4; ++mf)
#pragma unroll
      for (int nf = 0; nf < 2; ++nf)
#pragma unroll
        for (int kk = 0; kk < 2; ++kk)
          acc[mf][nf0 + nf] = __builtin_amdgcn_mfma_f32_16x16x32_f16(
              aF[mf * 2 + kk], bF[(nf0 + nf) * 2 + kk], acc[mf][nf0 + nf], 0, 0, 0);
  };

  stageT(0, 0);
  VMC(0);
  BAR();

#pragma unroll 1
  for (int t = 0; t < NK; ++t) {
    const int p = t & 1;
    if (t + 1 < NK) stageT(t * 64 + 64, p ^ 1);
    SB();
    ldA4(p); SB(); ldB2(p, 0); SB(); ldB2(p, 2); SB();
    LGKM(4); SB(); PRIO1(); burst(0); PRIO0(); SB();
    LGKM(0); SB(); PRIO1(); burst(2); PRIO0(); SB();
    if (t + 1 < NK) VMC(0);
    BAR();
  }

  const int r0 = row0 + wrow + u * 4;
  const int c0 = col0 + wcol + fr;
#pragma unroll
  for (int mf = 0; mf < 4; ++mf)
#pragma unroll
    for (int nf = 0; nf < 4; ++nf) {
      const int col = c0 + nf * 16;
      float badd = 0.f;
      if constexpr (MODE == 0) badd = bcat[col];
#pragma unroll
      for (int j = 0; j < 4; ++j) {
        const int row = r0 + mf * 16 + j;
        if constexpr (MODE == 2)
          C32[(size_t)row * CSTR + col] = acc[mf][nf][j];
        else
          C16[(size_t)row * CSTR + col] = (_Float16)(acc[mf][nf][j] + badd);
      }
    }
}

// --------- fused prep: x cvt (blocks 0..2047), W cvt (2048..3583), bias ------
__global__ __launch_bounds__(256) void prep(
    const float* __restrict__ x, const float* __restrict__ wq,
    const float* __restrict__ wk, const float* __restrict__ wv,
    const float* __restrict__ bq, const float* __restrict__ bk,
    const float* __restrict__ bv, _Float16* __restrict__ x16,
    _Float16* __restrict__ W16, float* __restrict__ bcat) {
  const int b = blockIdx.x, t = threadIdx.x;
  auto cv8 = [](const float* src, _Float16* dst) {
    const float4* p = (const float4*)src;
    float4 a = p[0], bb = p[1];
    half8 h;
    h[0] = (_Float16)a.x; h[1] = (_Float16)a.y; h[2] = (_Float16)a.z; h[3] = (_Float16)a.w;
    h[4] = (_Float16)bb.x; h[5] = (_Float16)bb.y; h[6] = (_Float16)bb.z; h[7] = (_Float16)bb.w;
    *(half8*)dst = h;
  };
  if (b < 2048) {
    const int i = b * 256 + t;
#pragma unroll
    for (int c = 0; c < 2; ++c) {
      const size_t j = (size_t)(i + c * 524288) * 8;
      cv8(x + j, x16 + j);
    }
  } else if (b < 3584) {
    const int idx = (b - 2048) * 256 + t;
    const int m = idx >> 17, j = idx & 131071;
    const float* src = m == 0 ? wq : (m == 1 ? wk : wv);
    cv8(src + (size_t)j * 8, W16 + (size_t)m * 1048576 + (size_t)j * 8);
  } else {
    const int i = (b - 3584) * 256 + t;
    const float* s = i < 1024 ? bq : (i < 2048 ? bk : bv);
    bcat[i] = s[i & 1023];
  }
}

// V = QKV cols 2048.. (stride 3072) -> Vt[4][1024][2048]
__global__ __launch_bounds__(256) void transpose_v(const _Float16* __restrict__ QKV,
                                                   _Float16* __restrict__ Vt) {
  __shared__ _Float16 t[32][36];
  const int b = blockIdx.z;
  const int e0 = blockIdx.x * 32;
  const int s0 = blockIdx.y * 32;
  const int tid = threadIdx.x;
  const int r = tid >> 3;
  const int c4 = (tid & 7) * 4;
  const _Float16* src = QKV + (size_t)(b * 2048 + s0 + r) * 3072 + 2048 + e0 + c4;
#pragma unroll
  for (int j = 0; j < 4; ++j) t[r][c4 + j] = src[j];
  __syncthreads();
  _Float16* dst = Vt + ((size_t)b * 1024 + e0 + r) * 2048 + s0 + c4;
#pragma unroll
  for (int j = 0; j < 4; ++j) dst[j] = t[c4 + j][r];
}

__global__ __launch_bounds__(256) void softmax_rows_f16(_Float16* __restrict__ S) {
  __shared__ float red[4];
  _Float16* s = S + (size_t)blockIdx.x * 2048;
  const int tid = threadIdx.x;
  float v[8];
  {
    half8 h = *(const half8*)(s + tid * 8);
#pragma unroll
    for (int j = 0; j < 8; ++j) v[j] = (float)h[j];
  }
  float m = v[0];
#pragma unroll
  for (int j = 1; j < 8; ++j) m = fmaxf(m, v[j]);
#pragma unroll
  for (int off = 32; off > 0; off >>= 1) m = fmaxf(m, __shfl_xor(m, off));
  if ((tid & 63) == 0) red[tid >> 6] = m;
  __syncthreads();
  m = fmaxf(fmaxf(red[0], red[1]), fmaxf(red[2], red[3]));
  float sum = 0.f;
#pragma unroll
  for (int j = 0; j < 8; ++j) { v[j] = __expf(v[j] - m); sum += v[j]; }
#pragma unroll
  for (int off = 32; off > 0; off >>= 1) sum += __shfl_xor(sum, off);
  __syncthreads();
  if ((tid & 63) == 0) red[tid >> 6] = sum;
  __syncthreads();
  sum = red[0] + red[1] + red[2] + red[3];
  const float inv = 1.0f / sum;
  half8 h;
#pragma unroll
  for (int j = 0; j < 8; ++j) h[j] = (_Float16)(v[j] * inv);
  *(half8*)(s + tid * 8) = h;
}

extern "C" void kernel_launch(void* const* d_in, const int* in_sizes, int n_in,
                              void* d_out, int out_size, void* d_ws, size_t ws_size,
                              hipStream_t stream) {
  (void)in_sizes; (void)n_in; (void)out_size;
  const float* x  = (const float*)d_in[0];
  const float* Wq = (const float*)d_in[1];
  const float* bq = (const float*)d_in[2];
  const float* Wk = (const float*)d_in[3];
  const float* bk = (const float*)d_in[4];
  const float* Wv = (const float*)d_in[5];
  const float* bv = (const float*)d_in[6];
  float* out = (float*)d_out;

  char* ws = (char*)d_ws;
  size_t off = 0;
  auto alloc = [&](size_t bytes) {
    char* p = ws + off;
    off += (bytes + 255) & ~255ull;
    return p;
  };
  _Float16* x16  = (_Float16*)alloc(8192ull * 1024 * 2);
  _Float16* W16  = (_Float16*)alloc(3072ull * 1024 * 2);
  _Float16* QKV  = (_Float16*)alloc(8192ull * 3072 * 2);
  _Float16* Vt   = (_Float16*)alloc(4096ull * 1024 * 4);
  _Float16* Sc   = (_Float16*)alloc(4ull * 2048 * 2048 * 2);
  float*    bcat = (float*)alloc(3072 * 4);
  if (off > ws_size) return;

  prep<<<3596, 256, 0, stream>>>(x, Wq, Wk, Wv, bq, bk, bv, x16, W16, bcat);

  gemmd<0><<<1536, 256, 0, stream>>>(x16, W16, QKV, bcat);
  transpose_v<<<dim3(32, 64, 4), 256, 0, stream>>>(QKV, Vt);

  gemm8x<<<256, 512, 0, stream>>>(QKV, Sc);
  softmax_rows_f16<<<8192, 256, 0, stream>>>(Sc);
  gemmd<2><<<512, 256, 0, stream>>>(Sc, Vt, out, nullptr);
}